// Round 8
// baseline (19.013 us; speedup 1.0000x reference)
//
#include <hip/hip_runtime.h>
#include <math.h>

#define N_NODES 21
#define NODE_FEAT 128
#define APAD 28          // padded row stride for 21-wide tiles
#define W1PAD 132        // padded row stride for 128-wide tiles

// Partial-buffer layout in ws (floats). All write-before-read (poison-safe).
#define WS_P1 0                   // [512 cols][64 blks]  c-major
#define WS_P2 (512 * 64)          // [512 cols][64 blks]  c-major
#define WS_P3 (2 * 512 * 64)      // [64 blks][256 cols]  blk-major
#define WS_NEED_BYTES ((2 * 512 * 64 + 64 * 256) * 4)

// Fallback (round-7) accumulator layout:
#define WS_ACC1 0
#define WS_ACC2 512
#define WS_ACC3 1024

// Monotonic epoch sync state (zero-init at module load; replay-safe).
__device__ unsigned g_arrive[64 * 16];   // 64B-strided arrival slots
__device__ unsigned g_go;
__device__ unsigned g_cnt;

__device__ __forceinline__ float agent_load(const float* p) {
    return __hip_atomic_load(p, __ATOMIC_RELAXED, __HIP_MEMORY_SCOPE_AGENT);
}
__device__ __forceinline__ void agent_store(float* p, float v) {
    __hip_atomic_store(p, v, __ATOMIC_RELAXED, __HIP_MEMORY_SCOPE_AGENT);
}
__device__ __forceinline__ unsigned flag_load(const unsigned* p) {
    return __hip_atomic_load(p, __ATOMIC_RELAXED, __HIP_MEMORY_SCOPE_AGENT);
}
__device__ __forceinline__ void flag_store(unsigned* p, unsigned v) {
    __hip_atomic_store(p, v, __ATOMIC_RELAXED, __HIP_MEMORY_SCOPE_AGENT);
}
__device__ __forceinline__ float agent_fadd(float* p, float v) {
    return __hip_atomic_fetch_add(p, v, __ATOMIC_RELAXED, __HIP_MEMORY_SCOPE_AGENT);
}

// Block barrier waiting ONLY on LDS ops: global loads stay in flight.
__device__ __forceinline__ void lds_barrier() {
    asm volatile("s_waitcnt lgkmcnt(0)\n\ts_barrier" ::: "memory");
}

// Hierarchical grid barrier; entry __syncthreads drains this block's
// stores (vmcnt 0) before the arrival flag.
__device__ __forceinline__ void grid_barrier(int blk, unsigned base, unsigned phase) {
    const unsigned target = base + phase;
    __syncthreads();
    if (blk == 0) {
        if (threadIdx.x > 0 && threadIdx.x < 64) {
            for (;;) {
                unsigned f = flag_load(&g_arrive[threadIdx.x * 16]);
                if ((int)(f - target) >= 0) break;
                __builtin_amdgcn_s_sleep(1);
            }
        }
        if (threadIdx.x == 0) flag_store(&g_go, target);
    } else {
        if (threadIdx.x == 0) {
            flag_store(&g_arrive[blk * 16], target);
            for (;;) {
                unsigned f = flag_load(&g_go);
                if ((int)(f - target) >= 0) break;
                __builtin_amdgcn_s_sleep(1);
            }
        }
    }
    __syncthreads();
}

// ======================= main kernel: partial buffers =======================
// 64 blocks x 512 threads. GCN redundant per block. FC stages row-split with
// PLAIN bypassing stores to per-block partial slots (no atomics, no zeroing,
// no zero-gate); post-barrier wave-per-column shuffle-tree reduces.
__global__ __launch_bounds__(512) void fused_kernel(
    const float* __restrict__ state, const int* __restrict__ edge_index,
    const float* __restrict__ W1, const float* __restrict__ b1,
    const float* __restrict__ W2, const float* __restrict__ b2,
    const float* __restrict__ Wf1, const float* __restrict__ bf1,
    const float* __restrict__ Wf2, const float* __restrict__ bf2,
    const float* __restrict__ Wf3, const float* __restrict__ bf3,
    float* __restrict__ ws, float* __restrict__ out)
{
    const int b = blockIdx.x;
    const int t = threadIdx.x;
    const int r6 = t >> 6, j6 = t & 63;     // wave / lane

    const unsigned bbase = flag_load(&g_go);
    const unsigned cbase = flag_load(&g_cnt);

    __shared__ float sA[21 * APAD];
    __shared__ float sX[21 * W1PAD];
    __shared__ float sW1T[21 * W1PAD];
    __shared__ float sW2T[21 * APAD];
    __shared__ float sT[21 * APAD];
    __shared__ float sG[21 * APAD];
    __shared__ float sv[441];
    __shared__ float sdeg[21];
    __shared__ float sb1[21], sb2[21];
    __shared__ float x1s[8], x2s[8];
    __shared__ float xs[512];
    __shared__ unsigned sflag;

    // ---- P0: zero tiles, stage X/W1T/W2T, edges, prefetch FC weights ----
    for (int i = t; i < 21 * APAD; i += 512) {
        sA[i] = 0.0f; sW2T[i] = 0.0f; sT[i] = 0.0f; sG[i] = 0.0f;
    }
    if (t < 21) { sdeg[t] = 1.0f; sb1[t] = b1[t]; sb2[t] = b2[t]; }
    {
        const float4* src4 = (const float4*)state;      // batch 0
        for (int i = t; i < 672; i += 512) {
            int n = i >> 5, fc = i & 31;
            ((float4*)&sX[n * W1PAD])[fc] = src4[i];
        }
    }
    for (int i = t; i < 2688; i += 512) {               // W1 -> sW1T[k][f]
        int f = i / 21, k = i - f * 21;
        sW1T[k * W1PAD + f] = W1[i];
    }
    for (int i = t; i < 441; i += 512) {                // W2 -> sW2T[k][f]
        int f = i / 21, k = i - f * 21;
        sW2T[k * APAD + f] = W2[i];
    }
    int er = 0, ec = 0;
    if (t < 128) { er = edge_index[t]; ec = edge_index[128 + t]; }

    // Coalesced row-prefetch of FC weights (block owns rows):
    float wf1v[7];
    if (b < 63) {
        #pragma unroll
        for (int i = 0; i < 7; ++i) wf1v[i] = Wf1[(size_t)(7 * b + i) * 512 + t];
    }
    float wf2v[8];
    #pragma unroll
    for (int i = 0; i < 8; ++i) wf2v[i] = Wf2[(size_t)(8 * b + i) * 512 + t];
    float wf3v[8];
    if (t < 256) {
        #pragma unroll
        for (int i = 0; i < 8; ++i) wf3v[i] = Wf3[(size_t)(8 * b + i) * 256 + t];
    }
    const float rbf1w = bf1[8 * b + r6];
    const float rbf2w = bf2[8 * b + r6];
    const float rbf3  = bf3[t & 255];

    lds_barrier();

    // ---- P1: adjacency scatter (+deg, +self-loop)  ||  h1 = X @ W1 ----
    if (t < 128) {
        atomicAdd(&sA[er * APAD + ec], 1.0f);
        atomicAdd(&sdeg[ec], 1.0f);
    }
    if (t < 21) atomicAdd(&sA[t * APAD + t], 1.0f);
    if (t < 441) {
        int n = t / 21, k = t - n * 21;
        const float4* x4 = (const float4*)&sX[n * W1PAD];
        const float4* w4 = (const float4*)&sW1T[k * W1PAD];
        float s = 0.0f;
        #pragma unroll
        for (int fc = 0; fc < 32; ++fc) {
            float4 a = x4[fc], ww = w4[fc];
            s += a.x * ww.x; s += a.y * ww.y; s += a.z * ww.z; s += a.w * ww.w;
        }
        sT[k * APAD + n] = s;
    }
    lds_barrier();

    // ---- P2: normalize A ----
    if (t < 441) {
        int r = t / 21, c = t - r * 21;
        float dr = 1.0f / sqrtf(sdeg[r]);
        float dc = 1.0f / sqrtf(sdeg[c]);
        sA[r * APAD + c] = dr * sA[r * APAD + c] * dc;
    }
    lds_barrier();

    // ---- P3: g1[i,k] = b1[k] + A[i,:] . h1T[k,:] ----
    if (t < 441) {
        int r = t / 21, k = t - r * 21;
        const float4* a4 = (const float4*)&sA[r * APAD];
        const float4* h4 = (const float4*)&sT[k * APAD];
        float s = sb1[k];
        #pragma unroll
        for (int jc = 0; jc < 6; ++jc) {
            float4 a = a4[jc], h = h4[jc];
            s += a.x * h.x; s += a.y * h.y; s += a.z * h.z; s += a.w * h.w;
        }
        sG[r * APAD + k] = s;
    }
    lds_barrier();

    // ---- P4: h2[n,k] = g1[n,:] . W2T[k,:] ----
    if (t < 441) {
        int n = t / 21, k = t - n * 21;
        const float4* g4 = (const float4*)&sG[n * APAD];
        const float4* w4 = (const float4*)&sW2T[k * APAD];
        float s = 0.0f;
        #pragma unroll
        for (int jc = 0; jc < 6; ++jc) {
            float4 g = g4[jc], ww = w4[jc];
            s += g.x * ww.x; s += g.y * ww.y; s += g.z * ww.z; s += g.w * ww.w;
        }
        sT[k * APAD + n] = s;
    }
    lds_barrier();

    // ---- P5: v[i*21+k] = b2[k] + A[i,:] . h2T[k,:] ----
    if (t < 441) {
        int r = t / 21, k = t - r * 21;
        const float4* a4 = (const float4*)&sA[r * APAD];
        const float4* h4 = (const float4*)&sT[k * APAD];
        float s = sb2[k];
        #pragma unroll
        for (int jc = 0; jc < 6; ++jc) {
            float4 a = a4[jc], h = h4[jc];
            s += a.x * h.x; s += a.y * h.y; s += a.z * h.z; s += a.w * h.w;
        }
        sv[t] = s;
    }
    lds_barrier();

    // ---- FC1: block b rows [7b,7b+7); PLAIN partial store (c-major) ----
    if (b < 63) {
        float s = 0.0f;
        #pragma unroll
        for (int r = 0; r < 7; ++r) s += sv[7 * b + r] * wf1v[r];
        agent_store(&ws[WS_P1 + t * 64 + b], s);
    }

    grid_barrier(b, bbase, 1);

    // ---- FC2: reduce 63 partials for cols [8b,8b+8), then row-split ----
    {
        float p = (j6 < 63) ? agent_load(&ws[WS_P1 + (8 * b + r6) * 64 + j6]) : 0.0f;
        #pragma unroll
        for (int m = 32; m; m >>= 1) p += __shfl_xor(p, m, 64);
        if (j6 == 0) x1s[r6] = fmaxf(p + rbf1w, 0.0f);
    }
    lds_barrier();
    {
        float s = 0.0f;
        #pragma unroll
        for (int j = 0; j < 8; ++j) s += x1s[j] * wf2v[j];
        agent_store(&ws[WS_P2 + t * 64 + b], s);
    }

    grid_barrier(b, bbase, 2);

    // ---- FC3: reduce 64 partials for cols [8b,8b+8), then row-split ----
    {
        float p = agent_load(&ws[WS_P2 + (8 * b + r6) * 64 + j6]);
        #pragma unroll
        for (int m = 32; m; m >>= 1) p += __shfl_xor(p, m, 64);
        if (j6 == 0) x2s[r6] = fmaxf(p + rbf2w, 0.0f);
    }
    lds_barrier();
    if (t < 256) {
        float s = 0.0f;
        #pragma unroll
        for (int j = 0; j < 8; ++j) s += x2s[j] * wf3v[j];
        agent_store(&ws[WS_P3 + b * 256 + t], s);
    }

    // ---- finale: completion count; 64th block reduces P3 -> out ----
    __syncthreads();                        // drain this block's P3 stores
    if (t == 0) {
        unsigned prev = __hip_atomic_fetch_add(&g_cnt, 1u, __ATOMIC_RELAXED,
                                               __HIP_MEMORY_SCOPE_AGENT);
        sflag = (prev == cbase + 63u) ? 1u : 0u;
    }
    __syncthreads();
    if (sflag) {
        const int c = t & 255, h = t >> 8;
        float s = 0.0f;
        #pragma unroll
        for (int j = 0; j < 32; ++j)
            s += agent_load(&ws[WS_P3 + (h * 32 + j) * 256 + c]);
        xs[t] = s;
    }
    lds_barrier();
    if (sflag && t < 256) out[t] = fmaxf(xs[t] + xs[t + 256] + rbf3, 0.0f);
}

// ======================= fallback: round-7 atomic kernel ====================
__global__ __launch_bounds__(512) void fused_kernel_atomic(
    const float* __restrict__ state, const int* __restrict__ edge_index,
    const float* __restrict__ W1, const float* __restrict__ b1,
    const float* __restrict__ W2, const float* __restrict__ b2,
    const float* __restrict__ Wf1, const float* __restrict__ bf1,
    const float* __restrict__ Wf2, const float* __restrict__ bf2,
    const float* __restrict__ Wf3, const float* __restrict__ bf3,
    float* __restrict__ ws, float* __restrict__ out)
{
    const int b = blockIdx.x;
    const int t = threadIdx.x;

    const unsigned bbase = flag_load(&g_go);
    const unsigned cbase = flag_load(&g_cnt);

    __shared__ float sA[21 * APAD];
    __shared__ float sX[21 * W1PAD];
    __shared__ float sW1T[21 * W1PAD];
    __shared__ float sW2T[21 * APAD];
    __shared__ float sT[21 * APAD];
    __shared__ float sG[21 * APAD];
    __shared__ float sv[441];
    __shared__ float sdeg[21];
    __shared__ float sb1[21], sb2[21];
    __shared__ float x1s[8], x2s[8];
    __shared__ unsigned sflag;

    for (int i = t; i < 21 * APAD; i += 512) {
        sA[i] = 0.0f; sW2T[i] = 0.0f; sT[i] = 0.0f; sG[i] = 0.0f;
    }
    if (t < 21) { sdeg[t] = 1.0f; sb1[t] = b1[t]; sb2[t] = b2[t]; }
    {
        const float4* src4 = (const float4*)state;
        for (int i = t; i < 672; i += 512) {
            int n = i >> 5, fc = i & 31;
            ((float4*)&sX[n * W1PAD])[fc] = src4[i];
        }
    }
    for (int i = t; i < 2688; i += 512) {
        int f = i / 21, k = i - f * 21;
        sW1T[k * W1PAD + f] = W1[i];
    }
    for (int i = t; i < 441; i += 512) {
        int f = i / 21, k = i - f * 21;
        sW2T[k * APAD + f] = W2[i];
    }
    int er = 0, ec = 0;
    if (t < 128) { er = edge_index[t]; ec = edge_index[128 + t]; }

    float wf1v[7];
    if (b < 63) {
        #pragma unroll
        for (int i = 0; i < 7; ++i) wf1v[i] = Wf1[(size_t)(7 * b + i) * 512 + t];
    }
    float wf2v[8];
    #pragma unroll
    for (int i = 0; i < 8; ++i) wf2v[i] = Wf2[(size_t)(8 * b + i) * 512 + t];
    float wf3v[8];
    if (t < 256) {
        #pragma unroll
        for (int i = 0; i < 8; ++i) wf3v[i] = Wf3[(size_t)(8 * b + i) * 256 + t];
    }
    const float rbf1 = (t < 8) ? bf1[8 * b + t] : 0.0f;
    const float rbf2 = (t < 8) ? bf2[8 * b + t] : 0.0f;
    const float rbf3 = bf3[t & 255];

    if (b == 0) {
        agent_store(&ws[WS_ACC1 + t], 0.0f);
        agent_store(&ws[WS_ACC2 + t], 0.0f);
        if (t < 256) agent_store(&ws[WS_ACC3 + t], 0.0f);
    }
    if (b == 0) __syncthreads(); else lds_barrier();
    if (b == 0 && t == 0) flag_store(&g_go, bbase + 1);

    if (t < 128) {
        atomicAdd(&sA[er * APAD + ec], 1.0f);
        atomicAdd(&sdeg[ec], 1.0f);
    }
    if (t < 21) atomicAdd(&sA[t * APAD + t], 1.0f);
    if (t < 441) {
        int n = t / 21, k = t - n * 21;
        const float4* x4 = (const float4*)&sX[n * W1PAD];
        const float4* w4 = (const float4*)&sW1T[k * W1PAD];
        float s = 0.0f;
        #pragma unroll
        for (int fc = 0; fc < 32; ++fc) {
            float4 a = x4[fc], ww = w4[fc];
            s += a.x * ww.x; s += a.y * ww.y; s += a.z * ww.z; s += a.w * ww.w;
        }
        sT[k * APAD + n] = s;
    }
    lds_barrier();
    if (t < 441) {
        int r = t / 21, c = t - r * 21;
        float dr = 1.0f / sqrtf(sdeg[r]);
        float dc = 1.0f / sqrtf(sdeg[c]);
        sA[r * APAD + c] = dr * sA[r * APAD + c] * dc;
    }
    lds_barrier();
    if (t < 441) {
        int r = t / 21, k = t - r * 21;
        const float4* a4 = (const float4*)&sA[r * APAD];
        const float4* h4 = (const float4*)&sT[k * APAD];
        float s = sb1[k];
        #pragma unroll
        for (int jc = 0; jc < 6; ++jc) {
            float4 a = a4[jc], h = h4[jc];
            s += a.x * h.x; s += a.y * h.y; s += a.z * h.z; s += a.w * h.w;
        }
        sG[r * APAD + k] = s;
    }
    lds_barrier();
    if (t < 441) {
        int n = t / 21, k = t - n * 21;
        const float4* g4 = (const float4*)&sG[n * APAD];
        const float4* w4 = (const float4*)&sW2T[k * APAD];
        float s = 0.0f;
        #pragma unroll
        for (int jc = 0; jc < 6; ++jc) {
            float4 g = g4[jc], ww = w4[jc];
            s += g.x * ww.x; s += g.y * ww.y; s += g.z * ww.z; s += g.w * ww.w;
        }
        sT[k * APAD + n] = s;
    }
    lds_barrier();
    if (t < 441) {
        int r = t / 21, k = t - r * 21;
        const float4* a4 = (const float4*)&sA[r * APAD];
        const float4* h4 = (const float4*)&sT[k * APAD];
        float s = sb2[k];
        #pragma unroll
        for (int jc = 0; jc < 6; ++jc) {
            float4 a = a4[jc], h = h4[jc];
            s += a.x * h.x; s += a.y * h.y; s += a.z * h.z; s += a.w * h.w;
        }
        sv[t] = s;
    }
    lds_barrier();

    if (t == 0) {
        while ((int)(flag_load(&g_go) - (bbase + 1)) < 0)
            __builtin_amdgcn_s_sleep(1);
    }
    __syncthreads();

    if (b < 63) {
        float s = 0.0f;
        #pragma unroll
        for (int r = 0; r < 7; ++r) s += sv[7 * b + r] * wf1v[r];
        agent_fadd(&ws[WS_ACC1 + t], s);
    }
    grid_barrier(b, bbase, 2);

    if (t < 8) x1s[t] = fmaxf(agent_load(&ws[WS_ACC1 + 8 * b + t]) + rbf1, 0.0f);
    lds_barrier();
    {
        float s = 0.0f;
        #pragma unroll
        for (int j = 0; j < 8; ++j) s += x1s[j] * wf2v[j];
        agent_fadd(&ws[WS_ACC2 + t], s);
    }
    grid_barrier(b, bbase, 3);

    if (t < 8) x2s[t] = fmaxf(agent_load(&ws[WS_ACC2 + 8 * b + t]) + rbf2, 0.0f);
    lds_barrier();
    if (t < 256) {
        float s = 0.0f;
        #pragma unroll
        for (int j = 0; j < 8; ++j) s += x2s[j] * wf3v[j];
        agent_fadd(&ws[WS_ACC3 + t], s);
    }

    __syncthreads();
    if (t == 0) {
        unsigned prev = __hip_atomic_fetch_add(&g_cnt, 1u, __ATOMIC_RELAXED,
                                               __HIP_MEMORY_SCOPE_AGENT);
        sflag = (prev == cbase + 63u) ? 1u : 0u;
    }
    __syncthreads();
    if (sflag && t < 256) {
        float a = agent_load(&ws[WS_ACC3 + t]) + rbf3;
        out[t] = fmaxf(a, 0.0f);
    }
}

extern "C" void kernel_launch(void* const* d_in, const int* in_sizes, int n_in,
                              void* d_out, int out_size, void* d_ws, size_t ws_size,
                              hipStream_t stream)
{
    const float* state      = (const float*)d_in[0];
    const int*   edge_index = (const int*)  d_in[1];
    const float* W1  = (const float*)d_in[2];
    const float* b1  = (const float*)d_in[3];
    const float* W2  = (const float*)d_in[4];
    const float* b2  = (const float*)d_in[5];
    const float* Wf1 = (const float*)d_in[6];
    const float* bf1 = (const float*)d_in[7];
    const float* Wf2 = (const float*)d_in[8];
    const float* bf2 = (const float*)d_in[9];
    const float* Wf3 = (const float*)d_in[10];
    const float* bf3 = (const float*)d_in[11];

    float* ws  = (float*)d_ws;
    float* out = (float*)d_out;

    if (ws_size >= (size_t)WS_NEED_BYTES) {
        fused_kernel<<<64, 512, 0, stream>>>(state, edge_index, W1, b1, W2, b2,
                                             Wf1, bf1, Wf2, bf2, Wf3, bf3, ws, out);
    } else {
        fused_kernel_atomic<<<64, 512, 0, stream>>>(state, edge_index, W1, b1, W2, b2,
                                                    Wf1, bf1, Wf2, bf2, Wf3, bf3, ws, out);
    }
}

// Round 10
// 16.382 us; speedup vs baseline: 1.1606x; 1.1606x over previous
//
#include <hip/hip_runtime.h>
#include <math.h>

#define N_NODES 21
#define NODE_FEAT 128
#define APAD 28          // padded row stride for 21-wide tiles
#define W1PAD 132        // padded row stride for 128-wide tiles

// ws float layout (acc zeroed by block 0 each launch; poison-safe):
#define WS_ACC1 0
#define WS_ACC2 512
#define WS_ACC3 1024

// Monotonic epoch sync state (zero-init at module load; replay-safe:
// every launch reads its own base first).
__device__ unsigned g_arrive[64 * 16];   // 64B-strided arrival slots
__device__ unsigned g_go;                // zero-ready(+1), bar1(+2), bar2(+3)
__device__ unsigned g_cnt;               // completion counter (finale trick)

// Agent-scope relaxed atomics: cache-bypassing ops served at the coherence
// point -> no L2 wb/inv fences needed anywhere.
__device__ __forceinline__ float agent_load(const float* p) {
    return __hip_atomic_load(p, __ATOMIC_RELAXED, __HIP_MEMORY_SCOPE_AGENT);
}
__device__ __forceinline__ void agent_store(float* p, float v) {
    __hip_atomic_store(p, v, __ATOMIC_RELAXED, __HIP_MEMORY_SCOPE_AGENT);
}
__device__ __forceinline__ unsigned flag_load(const unsigned* p) {
    return __hip_atomic_load(p, __ATOMIC_RELAXED, __HIP_MEMORY_SCOPE_AGENT);
}
__device__ __forceinline__ void flag_store(unsigned* p, unsigned v) {
    __hip_atomic_store(p, v, __ATOMIC_RELAXED, __HIP_MEMORY_SCOPE_AGENT);
}
__device__ __forceinline__ float agent_fadd(float* p, float v) {
    return __hip_atomic_fetch_add(p, v, __ATOMIC_RELAXED, __HIP_MEMORY_SCOPE_AGENT);
}

// Block barrier waiting ONLY on LDS ops (lgkmcnt): global prefetch loads
// stay in flight across it (__syncthreads would drain vmcnt(0)).
__device__ __forceinline__ void lds_barrier() {
    asm volatile("s_waitcnt lgkmcnt(0)\n\ts_barrier" ::: "memory");
}

// Hierarchical grid barrier; entry __syncthreads drains this block's
// data stores/atomics (vmcnt 0) before the arrival flag.
__device__ __forceinline__ void grid_barrier(int blk, unsigned base, unsigned phase) {
    const unsigned target = base + phase;
    __syncthreads();
    if (blk == 0) {
        if (threadIdx.x > 0 && threadIdx.x < 64) {
            for (;;) {
                unsigned f = flag_load(&g_arrive[threadIdx.x * 16]);
                if ((int)(f - target) >= 0) break;
                __builtin_amdgcn_s_sleep(1);
            }
        }
        if (threadIdx.x == 0) flag_store(&g_go, target);
    } else {
        if (threadIdx.x == 0) {
            flag_store(&g_arrive[blk * 16], target);
            for (;;) {
                unsigned f = flag_load(&g_go);
                if ((int)(f - target) >= 0) break;
                __builtin_amdgcn_s_sleep(1);
            }
        }
    }
    __syncthreads();
}

// Single launch, 64 blocks x 512 threads.
// IDENTICAL sync/GCN/zero-gate structure to the proven round-7 kernel; the
// ONLY change is the FC work maps (reduced atomic fan-in):
//   FC1: blocks 0..20  x 21 rows  (fan-in 63 -> 21)
//   FC2: blocks 21..52 x 16 rows  (fan-in 64 -> 32)
//   FC3: blocks 0..31  x 16 rows  (fan-in 64 -> 32)
__global__ __launch_bounds__(512) void fused_kernel(
    const float* __restrict__ state,      // [B,21,128], only batch 0 used
    const int*   __restrict__ edge_index, // [2,128]
    const float* __restrict__ W1,         // [128,21]
    const float* __restrict__ b1,         // [21]
    const float* __restrict__ W2,         // [21,21]
    const float* __restrict__ b2,         // [21]
    const float* __restrict__ Wf1,        // [441,512]
    const float* __restrict__ bf1,        // [512]
    const float* __restrict__ Wf2,        // [512,512]
    const float* __restrict__ bf2,        // [512]
    const float* __restrict__ Wf3,        // [512,256]
    const float* __restrict__ bf3,        // [256]
    float* __restrict__ ws,
    float* __restrict__ out)
{
    const int b = blockIdx.x;
    const int t = threadIdx.x;

    const unsigned bbase = flag_load(&g_go);
    const unsigned cbase = flag_load(&g_cnt);

    const bool do_fc1 = (b < 21);
    const bool do_fc2 = (b >= 21 && b < 53);
    const bool do_fc3 = (b < 32);

    // ---------------- LDS ----------------
    __shared__ float sA[21 * APAD];
    __shared__ float sX[21 * W1PAD];
    __shared__ float sW1T[21 * W1PAD];
    __shared__ float sW2T[21 * APAD];
    __shared__ float sT[21 * APAD];      // h1T then h2T
    __shared__ float sG[21 * APAD];      // g1
    __shared__ float sv[441];
    __shared__ float sdeg[21];
    __shared__ float sb1[21], sb2[21];
    __shared__ float x1s[16], x2s[16];
    __shared__ unsigned sflag;

    // ---- P0: zero tiles, stage X/W1T/W2T, load edges, prefetch weights ----
    for (int i = t; i < 21 * APAD; i += 512) {
        sA[i] = 0.0f; sW2T[i] = 0.0f; sT[i] = 0.0f; sG[i] = 0.0f;
    }
    if (t < 21) { sdeg[t] = 1.0f; sb1[t] = b1[t]; sb2[t] = b2[t]; }
    {
        const float4* src4 = (const float4*)state;      // batch 0
        for (int i = t; i < 672; i += 512) {            // 21*128/4
            int n = i >> 5, fc = i & 31;
            ((float4*)&sX[n * W1PAD])[fc] = src4[i];
        }
    }
    for (int i = t; i < 2688; i += 512) {               // W1 -> sW1T[k][f]
        int f = i / 21, k = i - f * 21;
        sW1T[k * W1PAD + f] = W1[i];
    }
    for (int i = t; i < 441; i += 512) {                // W2 -> sW2T[k][f]
        int f = i / 21, k = i - f * 21;
        sW2T[k * APAD + f] = W2[i];
    }
    int er = 0, ec = 0;
    if (t < 128) { er = edge_index[t]; ec = edge_index[128 + t]; }

    // Coalesced row-prefetch of FC weights (per role):
    float wf1v[21];
    if (do_fc1) {
        #pragma unroll
        for (int i = 0; i < 21; ++i) wf1v[i] = Wf1[(size_t)(21 * b + i) * 512 + t];
    }
    float wf2v[16];
    float rbf1 = 0.0f;
    if (do_fc2) {
        #pragma unroll
        for (int i = 0; i < 16; ++i) wf2v[i] = Wf2[(size_t)(16 * (b - 21) + i) * 512 + t];
        if (t < 16) rbf1 = bf1[16 * (b - 21) + t];
    }
    float wf3v[16];
    float rbf2 = 0.0f;
    if (do_fc3) {
        if (t < 256) {
            #pragma unroll
            for (int i = 0; i < 16; ++i) wf3v[i] = Wf3[(size_t)(16 * b + i) * 256 + t];
        }
        if (t < 16) rbf2 = bf2[16 * b + t];
    }
    const float rbf3 = bf3[t & 255];

    // Block 0 zeroes the split-K accumulators (bypassing stores).
    if (b == 0) {
        agent_store(&ws[WS_ACC1 + t], 0.0f);
        agent_store(&ws[WS_ACC2 + t], 0.0f);
        if (t < 256) agent_store(&ws[WS_ACC3 + t], 0.0f);
    }

    // b1: block 0 uses __syncthreads (drains its zero stores); others lgkm-only.
    if (b == 0) __syncthreads(); else lds_barrier();
    if (b == 0 && t == 0) flag_store(&g_go, bbase + 1);   // zero-ready

    // ---- P1: adjacency scatter (+deg, +self-loop)  ||  h1 = X @ W1 ----
    if (t < 128) {
        atomicAdd(&sA[er * APAD + ec], 1.0f);
        atomicAdd(&sdeg[ec], 1.0f);
    }
    if (t < 21) atomicAdd(&sA[t * APAD + t], 1.0f);
    if (t < 441) {
        int n = t / 21, k = t - n * 21;
        const float4* x4 = (const float4*)&sX[n * W1PAD];
        const float4* w4 = (const float4*)&sW1T[k * W1PAD];
        float s = 0.0f;
        #pragma unroll
        for (int fc = 0; fc < 32; ++fc) {
            float4 a = x4[fc], ww = w4[fc];
            s += a.x * ww.x; s += a.y * ww.y; s += a.z * ww.z; s += a.w * ww.w;
        }
        sT[k * APAD + n] = s;
    }
    lds_barrier();

    // ---- P2: normalize A (dinv inlined) ----
    if (t < 441) {
        int r = t / 21, c = t - r * 21;
        float dr = 1.0f / sqrtf(sdeg[r]);
        float dc = 1.0f / sqrtf(sdeg[c]);
        sA[r * APAD + c] = dr * sA[r * APAD + c] * dc;
    }
    lds_barrier();

    // ---- P3: g1[i,k] = b1[k] + A[i,:] . h1T[k,:] ----
    if (t < 441) {
        int r = t / 21, k = t - r * 21;
        const float4* a4 = (const float4*)&sA[r * APAD];
        const float4* h4 = (const float4*)&sT[k * APAD];
        float s = sb1[k];
        #pragma unroll
        for (int jc = 0; jc < 6; ++jc) {
            float4 a = a4[jc], h = h4[jc];
            s += a.x * h.x; s += a.y * h.y; s += a.z * h.z; s += a.w * h.w;
        }
        sG[r * APAD + k] = s;
    }
    lds_barrier();

    // ---- P4: h2[n,k] = g1[n,:] . W2T[k,:] ----
    if (t < 441) {
        int n = t / 21, k = t - n * 21;
        const float4* g4 = (const float4*)&sG[n * APAD];
        const float4* w4 = (const float4*)&sW2T[k * APAD];
        float s = 0.0f;
        #pragma unroll
        for (int jc = 0; jc < 6; ++jc) {
            float4 g = g4[jc], ww = w4[jc];
            s += g.x * ww.x; s += g.y * ww.y; s += g.z * ww.z; s += g.w * ww.w;
        }
        sT[k * APAD + n] = s;
    }
    lds_barrier();

    // ---- P5: v[i*21+k] = b2[k] + A[i,:] . h2T[k,:] ----
    if (t < 441) {
        int r = t / 21, k = t - r * 21;
        const float4* a4 = (const float4*)&sA[r * APAD];
        const float4* h4 = (const float4*)&sT[k * APAD];
        float s = sb2[k];
        #pragma unroll
        for (int jc = 0; jc < 6; ++jc) {
            float4 a = a4[jc], h = h4[jc];
            s += a.x * h.x; s += a.y * h.y; s += a.z * h.z; s += a.w * h.w;
        }
        sv[t] = s;
    }
    lds_barrier();

    // ---- zero-ready gate (set long ago; ~one poll) ----
    if (t == 0) {
        while ((int)(flag_load(&g_go) - (bbase + 1)) < 0)
            __builtin_amdgcn_s_sleep(1);
    }
    __syncthreads();

    // ---- FC1 (row-split): blocks 0..20, rows [21b, 21b+21) ----
    if (do_fc1) {
        float s = 0.0f;
        #pragma unroll
        for (int r = 0; r < 21; ++r) s += sv[21 * b + r] * wf1v[r];
        agent_fadd(&ws[WS_ACC1 + t], s);
    }

    grid_barrier(b, bbase, 2);

    // ---- FC2 (row-split): blocks 21..52, rows [16(b-21), +16) ----
    if (do_fc2) {
        if (t < 16)
            x1s[t] = fmaxf(agent_load(&ws[WS_ACC1 + 16 * (b - 21) + t]) + rbf1, 0.0f);
        lds_barrier();
        float s = 0.0f;
        #pragma unroll
        for (int j = 0; j < 16; ++j) s += x1s[j] * wf2v[j];
        agent_fadd(&ws[WS_ACC2 + t], s);
    }

    grid_barrier(b, bbase, 3);

    // ---- FC3 (row-split): blocks 0..31, rows [16b, 16b+16), cols 0..255 ----
    if (do_fc3) {
        if (t < 16)
            x2s[t] = fmaxf(agent_load(&ws[WS_ACC2 + 16 * b + t]) + rbf2, 0.0f);
        lds_barrier();
        if (t < 256) {
            float s = 0.0f;
            #pragma unroll
            for (int j = 0; j < 16; ++j) s += x2s[j] * wf3v[j];
            agent_fadd(&ws[WS_ACC3 + t], s);
        }
    }

    // ---- finale: completion-count; the 64th block finalizes ----
    __syncthreads();                       // drain this block's FC3 adds
    if (t == 0) {
        unsigned prev = __hip_atomic_fetch_add(&g_cnt, 1u, __ATOMIC_RELAXED,
                                               __HIP_MEMORY_SCOPE_AGENT);
        sflag = (prev == cbase + 63u) ? 1u : 0u;
    }
    __syncthreads();
    if (sflag && t < 256) {
        float a = agent_load(&ws[WS_ACC3 + t]) + rbf3;
        out[t] = fmaxf(a, 0.0f);
    }
}

extern "C" void kernel_launch(void* const* d_in, const int* in_sizes, int n_in,
                              void* d_out, int out_size, void* d_ws, size_t ws_size,
                              hipStream_t stream)
{
    const float* state      = (const float*)d_in[0];
    const int*   edge_index = (const int*)  d_in[1];
    const float* W1  = (const float*)d_in[2];
    const float* b1  = (const float*)d_in[3];
    const float* W2  = (const float*)d_in[4];
    const float* b2  = (const float*)d_in[5];
    const float* Wf1 = (const float*)d_in[6];
    const float* bf1 = (const float*)d_in[7];
    const float* Wf2 = (const float*)d_in[8];
    const float* bf2 = (const float*)d_in[9];
    const float* Wf3 = (const float*)d_in[10];
    const float* bf3 = (const float*)d_in[11];

    float* ws  = (float*)d_ws;
    float* out = (float*)d_out;

    fused_kernel<<<64, 512, 0, stream>>>(state, edge_index, W1, b1, W2, b2,
                                         Wf1, bf1, Wf2, bf2, Wf3, bf3, ws, out);
}

// Round 11
// 16.178 us; speedup vs baseline: 1.1753x; 1.0126x over previous
//
#include <hip/hip_runtime.h>
#include <math.h>

#define APAD 28          // padded row stride for 21-wide tiles
#define W1PAD 132        // padded row stride for 128-wide tiles

// ws float layout (acc zeroed by block 63 each launch; poison-safe):
#define WS_ACC1 0
#define WS_ACC2 512
#define WS_ACC3 1024

// Reset-based sync state: all words are 0 at module load, and the finalizer
// block restores every word to 0 before kernel end (stream ordering + the
// end-of-dispatch release fence make this visible to the next launch).
// -> no epoch arithmetic, no read-your-base races, graph/replay-safe.
__device__ unsigned g_arrive[64 * 16];   // 64B-strided arrival slots, phase 0/1/2
__device__ unsigned g_go;                // barrier release word
__device__ unsigned g_zr;                // accumulators-zeroed flag
__device__ unsigned g_cnt;               // finale completion counter

// Agent-scope relaxed atomics: cache-bypassing ops served at the coherence
// point -> no L2 wb/inv fences needed anywhere.
__device__ __forceinline__ float agent_load(const float* p) {
    return __hip_atomic_load(p, __ATOMIC_RELAXED, __HIP_MEMORY_SCOPE_AGENT);
}
__device__ __forceinline__ void agent_store(float* p, float v) {
    __hip_atomic_store(p, v, __ATOMIC_RELAXED, __HIP_MEMORY_SCOPE_AGENT);
}
__device__ __forceinline__ unsigned flag_load(const unsigned* p) {
    return __hip_atomic_load(p, __ATOMIC_RELAXED, __HIP_MEMORY_SCOPE_AGENT);
}
__device__ __forceinline__ void flag_store(unsigned* p, unsigned v) {
    __hip_atomic_store(p, v, __ATOMIC_RELAXED, __HIP_MEMORY_SCOPE_AGENT);
}
__device__ __forceinline__ float agent_fadd(float* p, float v) {
    return __hip_atomic_fetch_add(p, v, __ATOMIC_RELAXED, __HIP_MEMORY_SCOPE_AGENT);
}

// Block barrier waiting ONLY on LDS ops (lgkmcnt): global prefetch loads
// stay in flight across it (__syncthreads would drain vmcnt(0)).
__device__ __forceinline__ void lds_barrier() {
    asm volatile("s_waitcnt lgkmcnt(0)\n\ts_barrier" ::: "memory");
}

// Hierarchical grid barrier, phase = 1 then 2. Entry __syncthreads drains
// this block's stores/atomics (vmcnt 0) before the arrival flag.
__device__ __forceinline__ void grid_barrier(int blk, unsigned phase) {
    __syncthreads();
    if (blk == 0) {
        if (threadIdx.x > 0 && threadIdx.x < 64) {
            while (flag_load(&g_arrive[threadIdx.x * 16]) < phase)
                __builtin_amdgcn_s_sleep(1);
        }
        if (threadIdx.x == 0) flag_store(&g_go, phase);
    } else {
        if (threadIdx.x == 0) {
            flag_store(&g_arrive[blk * 16], phase);
            while (flag_load(&g_go) < phase)
                __builtin_amdgcn_s_sleep(1);
        }
    }
    __syncthreads();
}

// Single launch, 64 blocks x 512 threads, role-split:
//   blocks 0-20 : GCN (own row) + FC1 rows [21b, 21b+21)   (fan-in 21)
//   blocks 21-36: FC2 rows [32(b-21), +32)                 (fan-in 16)
//   blocks 37-44: FC3 rows [64(b-37), +64)                 (fan-in 8)
//   block 63    : zeroes acc1/acc2/acc3, sets g_zr
//   blocks 45-62: barrier participants only
// Barriers: FC1 -> bar(1) -> FC2 -> bar(2) -> FC3 -> completion-count finale.
// FC1 adds are gated on g_zr (zeros visible); FC2/FC3 adds are ordered by
// block 63's bar(1)/bar(2) arrivals.
__global__ __launch_bounds__(512) void fused_kernel(
    const float* __restrict__ state,      // [B,21,128], only batch 0 used
    const int*   __restrict__ edge_index, // [2,128]
    const float* __restrict__ W1,         // [128,21]
    const float* __restrict__ b1,         // [21]
    const float* __restrict__ W2,         // [21,21]
    const float* __restrict__ b2,         // [21]
    const float* __restrict__ Wf1,        // [441,512]
    const float* __restrict__ bf1,        // [512]
    const float* __restrict__ Wf2,        // [512,512]
    const float* __restrict__ bf2,        // [512]
    const float* __restrict__ Wf3,        // [512,256]
    const float* __restrict__ bf3,        // [256]
    float* __restrict__ ws,
    float* __restrict__ out)
{
    const int b = blockIdx.x;
    const int t = threadIdx.x;

    const bool is_gcn = (b < 21);                 // also the FC1 blocks
    const bool do_fc2 = (b >= 21 && b < 37);
    const bool do_fc3 = (b >= 37 && b < 45);

    // ---------------- LDS ----------------
    __shared__ float sA[21 * APAD];
    __shared__ float sX[21 * W1PAD];
    __shared__ float sW1T[21 * W1PAD];
    __shared__ float sW2T[21 * APAD];
    __shared__ float sT[21 * APAD];      // h1T then h2T
    __shared__ float sG[21 * APAD];      // g1
    __shared__ float sv[441];
    __shared__ float sdeg[21];
    __shared__ float sb1[21], sb2[21];
    __shared__ float x1s[32], x2s[64];
    __shared__ unsigned sflag;

    // ---------------- role prefetches (coalesced row reads) ----------------
    float wf1v[21];
    if (is_gcn) {
        #pragma unroll
        for (int i = 0; i < 21; ++i) wf1v[i] = Wf1[(size_t)(21 * b + i) * 512 + t];
    }
    float wf2v[32];
    float rbf1 = 0.0f;
    if (do_fc2) {
        #pragma unroll
        for (int i = 0; i < 32; ++i) wf2v[i] = Wf2[(size_t)(32 * (b - 21) + i) * 512 + t];
        if (t < 32) rbf1 = bf1[32 * (b - 21) + t];
    }
    float wf3v[64];
    float rbf2 = 0.0f;
    if (do_fc3) {
        if (t < 256) {
            #pragma unroll
            for (int i = 0; i < 64; ++i) wf3v[i] = Wf3[(size_t)(64 * (b - 37) + i) * 256 + t];
        }
        if (t < 64) rbf2 = bf2[64 * (b - 37) + t];
    }
    const float rbf3 = bf3[t & 255];   // any block may finalize

    // ---------------- zeroer: block 63 ----------------
    if (b == 63) {
        agent_store(&ws[WS_ACC1 + t], 0.0f);
        agent_store(&ws[WS_ACC2 + t], 0.0f);
        if (t < 256) agent_store(&ws[WS_ACC3 + t], 0.0f);
        __syncthreads();                          // drain zero stores (vmcnt 0)
        if (t == 0) flag_store(&g_zr, 1u);        // zeros globally visible
    }

    // ---------------- GCN: blocks 0..20 only (round-10 phases verbatim) ----
    if (is_gcn) {
        // P0: zero pads, stage X/W1T/W2T, edges
        for (int i = t; i < 21 * APAD; i += 512) {
            sA[i] = 0.0f; sW2T[i] = 0.0f; sT[i] = 0.0f; sG[i] = 0.0f;
        }
        if (t < 21) { sdeg[t] = 1.0f; sb1[t] = b1[t]; sb2[t] = b2[t]; }
        {
            const float4* src4 = (const float4*)state;      // batch 0
            for (int i = t; i < 672; i += 512) {            // 21*128/4
                int n = i >> 5, fc = i & 31;
                ((float4*)&sX[n * W1PAD])[fc] = src4[i];
            }
        }
        for (int i = t; i < 2688; i += 512) {               // W1 -> sW1T[k][f]
            int f = i / 21, k = i - f * 21;
            sW1T[k * W1PAD + f] = W1[i];
        }
        for (int i = t; i < 441; i += 512) {                // W2 -> sW2T[k][f]
            int f = i / 21, k = i - f * 21;
            sW2T[k * APAD + f] = W2[i];
        }
        int er = 0, ec = 0;
        if (t < 128) { er = edge_index[t]; ec = edge_index[128 + t]; }
        lds_barrier();

        // P1: adjacency scatter (+deg, +self-loop)  ||  h1 = X @ W1
        if (t < 128) {
            atomicAdd(&sA[er * APAD + ec], 1.0f);
            atomicAdd(&sdeg[ec], 1.0f);
        }
        if (t < 21) atomicAdd(&sA[t * APAD + t], 1.0f);
        if (t < 441) {
            int n = t / 21, k = t - n * 21;
            const float4* x4 = (const float4*)&sX[n * W1PAD];
            const float4* w4 = (const float4*)&sW1T[k * W1PAD];
            float s = 0.0f;
            #pragma unroll
            for (int fc = 0; fc < 32; ++fc) {
                float4 a = x4[fc], ww = w4[fc];
                s += a.x * ww.x; s += a.y * ww.y; s += a.z * ww.z; s += a.w * ww.w;
            }
            sT[k * APAD + n] = s;
        }
        lds_barrier();

        // P2: normalize A
        if (t < 441) {
            int r = t / 21, c = t - r * 21;
            float dr = 1.0f / sqrtf(sdeg[r]);
            float dc = 1.0f / sqrtf(sdeg[c]);
            sA[r * APAD + c] = dr * sA[r * APAD + c] * dc;
        }
        lds_barrier();

        // P3: g1[i,k] = b1[k] + A[i,:] . h1T[k,:]
        if (t < 441) {
            int r = t / 21, k = t - r * 21;
            const float4* a4 = (const float4*)&sA[r * APAD];
            const float4* h4 = (const float4*)&sT[k * APAD];
            float s = sb1[k];
            #pragma unroll
            for (int jc = 0; jc < 6; ++jc) {
                float4 a = a4[jc], h = h4[jc];
                s += a.x * h.x; s += a.y * h.y; s += a.z * h.z; s += a.w * h.w;
            }
            sG[r * APAD + k] = s;
        }
        lds_barrier();

        // P4: h2[n,k] = g1[n,:] . W2T[k,:]
        if (t < 441) {
            int n = t / 21, k = t - n * 21;
            const float4* g4 = (const float4*)&sG[n * APAD];
            const float4* w4 = (const float4*)&sW2T[k * APAD];
            float s = 0.0f;
            #pragma unroll
            for (int jc = 0; jc < 6; ++jc) {
                float4 g = g4[jc], ww = w4[jc];
                s += g.x * ww.x; s += g.y * ww.y; s += g.z * ww.z; s += g.w * ww.w;
            }
            sT[k * APAD + n] = s;
        }
        lds_barrier();

        // P5: v[i*21+k] = b2[k] + A[i,:] . h2T[k,:]
        if (t < 441) {
            int r = t / 21, k = t - r * 21;
            const float4* a4 = (const float4*)&sA[r * APAD];
            const float4* h4 = (const float4*)&sT[k * APAD];
            float s = sb2[k];
            #pragma unroll
            for (int jc = 0; jc < 6; ++jc) {
                float4 a = a4[jc], h = h4[jc];
                s += a.x * h.x; s += a.y * h.y; s += a.z * h.z; s += a.w * h.w;
            }
            sv[t] = s;
        }
        lds_barrier();

        // zero-ready gate (block 63 set g_zr ~4µs ago; ~one poll)
        if (t == 0) {
            while (flag_load(&g_zr) == 0u) __builtin_amdgcn_s_sleep(1);
        }
        __syncthreads();

        // FC1 (row-split): rows [21b, 21b+21)
        {
            float s = 0.0f;
            #pragma unroll
            for (int r = 0; r < 21; ++r) s += sv[21 * b + r] * wf1v[r];
            agent_fadd(&ws[WS_ACC1 + t], s);
        }
    }

    grid_barrier(b, 1);   // acc1 complete (and acc2/acc3 zeros via block 63)

    // ---------------- FC2: blocks 21..36, rows [32(b-21), +32) -------------
    if (do_fc2) {
        if (t < 32)
            x1s[t] = fmaxf(agent_load(&ws[WS_ACC1 + 32 * (b - 21) + t]) + rbf1, 0.0f);
        lds_barrier();
        float s = 0.0f;
        #pragma unroll
        for (int j = 0; j < 32; ++j) s += x1s[j] * wf2v[j];
        agent_fadd(&ws[WS_ACC2 + t], s);
    }

    grid_barrier(b, 2);   // acc2 complete

    // ---------------- FC3: blocks 37..44, rows [64(b-37), +64) -------------
    if (do_fc3) {
        if (t < 64)
            x2s[t] = fmaxf(agent_load(&ws[WS_ACC2 + 64 * (b - 37) + t]) + rbf2, 0.0f);
        lds_barrier();
        if (t < 256) {
            float s = 0.0f;
            #pragma unroll
            for (int j = 0; j < 64; ++j) s += x2s[j] * wf3v[j];
            agent_fadd(&ws[WS_ACC3 + t], s);
        }
    }

    // ---------------- finale: completion count; 64th block finalizes -------
    __syncthreads();                        // drain this block's FC3 adds
    if (t == 0) {
        unsigned prev = __hip_atomic_fetch_add(&g_cnt, 1u, __ATOMIC_RELAXED,
                                               __HIP_MEMORY_SCOPE_AGENT);
        sflag = (prev == 63u) ? 1u : 0u;
    }
    __syncthreads();
    if (sflag) {
        if (t < 256) {
            float a = agent_load(&ws[WS_ACC3 + t]) + rbf3;
            out[t] = fmaxf(a, 0.0f);
        }
        // Restore ALL sync words to 0 for the next launch. Every use of these
        // words in this launch happens-before the 64th g_cnt increment, and
        // the end-of-dispatch release publishes the resets before the next
        // kernel on this stream can start.
        if (t >= 256 && t < 320) flag_store(&g_arrive[(t - 256) * 16], 0u);
        if (t == 320) flag_store(&g_go, 0u);
        if (t == 321) flag_store(&g_zr, 0u);
        if (t == 322) flag_store(&g_cnt, 0u);
    }
}

extern "C" void kernel_launch(void* const* d_in, const int* in_sizes, int n_in,
                              void* d_out, int out_size, void* d_ws, size_t ws_size,
                              hipStream_t stream)
{
    const float* state      = (const float*)d_in[0];
    const int*   edge_index = (const int*)  d_in[1];
    const float* W1  = (const float*)d_in[2];
    const float* b1  = (const float*)d_in[3];
    const float* W2  = (const float*)d_in[4];
    const float* b2  = (const float*)d_in[5];
    const float* Wf1 = (const float*)d_in[6];
    const float* bf1 = (const float*)d_in[7];
    const float* Wf2 = (const float*)d_in[8];
    const float* bf2 = (const float*)d_in[9];
    const float* Wf3 = (const float*)d_in[10];
    const float* bf3 = (const float*)d_in[11];

    float* ws  = (float*)d_ws;
    float* out = (float*)d_out;

    fused_kernel<<<64, 512, 0, stream>>>(state, edge_index, W1, b1, W2, b2,
                                         Wf1, bf1, Wf2, bf2, Wf3, bf3, ws, out);
}